// Round 12
// baseline (33.072 us; speedup 1.0000x reference)
//
#include <hip/hip_runtime.h>
#include <hip/hip_bf16.h>

// x: (N=8, C=512, T=32, H=14, W=14) fp32 = 131072 rows x 196 floats.
// R9 structure (best: 23.02 us) + NONTEMPORAL loads on the x stream.
// Block = (n, 32 owned channels, 2 timesteps): 8*16*16 = 2048 blocks, 256 thr.
// Phase 1: GAP for (32+4 halo) channels x 2 t = 72 rows; 4 threads per row
//   (quad scheme: strided float4-nt, 2x shfl_xor), 2 passes -> LDS[72].
// Phase 2: threads 0..63 compute the 5-tap channel conv + sigmoid from LDS.

#define F4_PER_ROW 49
#define CH 32
#define TBLK 2
#define HALO 2
#define ROWS_TOT ((CH + 2 * HALO) * TBLK)   // 72

typedef float f32x4 __attribute__((ext_vector_type(4)));

__device__ __forceinline__ f32x4 ldnt(const f32x4* p) {
    return __builtin_nontemporal_load(p);
}

__global__ __launch_bounds__(256, 8) void fused_halo_nt_kernel(
        const float* __restrict__ x,
        const float* __restrict__ w,
        float* __restrict__ out) {
    const int bid = blockIdx.x;
    const int n   = bid >> 8;          // 256 blocks per image
    const int cb  = (bid >> 4) & 15;   // channel tile
    const int tb  = bid & 15;          // t tile
    const int c0  = cb * CH;
    const int t0  = tb * TBLK;

    const int tid = threadIdx.x;
    const int q   = tid & 3;

    __shared__ float gs[ROWS_TOT];

    #pragma unroll
    for (int pass = 0; pass < 2; ++pass) {
        const int ri = pass * 64 + (tid >> 2);
        if (ri < ROWS_TOT) {
            const int ci = ri >> 1;            // 0..35 (c = c0-2+ci)
            const int tj = ri & 1;
            const int c  = c0 - HALO + ci;
            float sum = 0.0f;
            if (c >= 0 && c < 512) {
                const int row = (n * 512 + c) * 32 + t0 + tj;
                const f32x4* p = reinterpret_cast<const f32x4*>(x) +
                                 (size_t)row * F4_PER_ROW + q;
                f32x4 a0 = ldnt(p);
                f32x4 a1 = ldnt(p + 4);
                #pragma unroll
                for (int i = 2; i < 12; i += 2) {
                    f32x4 u = ldnt(p + 4 * i);
                    f32x4 v = ldnt(p + 4 * (i + 1));
                    a0 += u;
                    a1 += v;
                }
                f32x4 a = a0 + a1;
                sum = (a.x + a.y) + (a.z + a.w);
                if (q == 0) {
                    f32x4 u = ldnt(p + 48);
                    sum += (u.x + u.y) + (u.z + u.w);
                }
            }
            sum += __shfl_xor(sum, 1, 64);
            sum += __shfl_xor(sum, 2, 64);
            if (q == 0) gs[ri] = sum * (1.0f / 196.0f);
        }
    }
    __syncthreads();

    // Phase 2: 64 outputs (32 channels x 2 t), one per thread.
    if (tid < CH * TBLK) {
        const int ci = tid >> 1;   // owned channel index 0..31
        const int tj = tid & 1;
        const float acc =
            w[0] * gs[(ci + 0) * TBLK + tj] +
            w[1] * gs[(ci + 1) * TBLK + tj] +
            w[2] * gs[(ci + 2) * TBLK + tj] +
            w[3] * gs[(ci + 3) * TBLK + tj] +
            w[4] * gs[(ci + 4) * TBLK + tj];
        out[(n * 512 + c0 + ci) * 32 + t0 + tj] = 1.0f / (1.0f + __expf(-acc));
    }
}

extern "C" void kernel_launch(void* const* d_in, const int* in_sizes, int n_in,
                              void* d_out, int out_size, void* d_ws, size_t ws_size,
                              hipStream_t stream) {
    const float* x = (const float*)d_in[0];   // 8*512*32*14*14
    const float* w = (const float*)d_in[1];   // 5
    float* out = (float*)d_out;               // 8*512*32

    fused_halo_nt_kernel<<<2048, 256, 0, stream>>>(x, w, out);
}

// Round 13
// 22.799 us; speedup vs baseline: 1.4506x; 1.4506x over previous
//
#include <hip/hip_runtime.h>
#include <hip/hip_bf16.h>

// x: (N=8, C=512, T=32, H=14, W=14) fp32 contiguous = 131072 rows x 196 floats.
// FINAL (revert to R9, best measured: 23.02 us).
// Single fused kernel, halo recompute, no cross-block sync.
// Block = (n, 32 owned channels, 2 timesteps): 8*16*16 = 2048 blocks, 256 thr,
//   8 blocks/CU (full 32 waves/CU occupancy).
// Phase 1: GAP for (32+4 halo) channels x 2 t = 72 rows; 4 threads per row
//   (quad scheme: strided float4, 2x shfl_xor quad-combine), 2 passes -> LDS[72].
//   Channels outside [0,512) contribute 0 (zero padding of the conv).
// Phase 2: threads 0..63 compute the 5-tap channel conv + sigmoid from LDS.
// Measured plateau across 8 structural variants: ~5.0-5.1 TB/s logical read
// = ~10 B/cyc/CU streaming-read path limit (matches m13 constant). Roofline.

#define F4_PER_ROW 49
#define CH 32
#define TBLK 2
#define HALO 2
#define ROWS_TOT ((CH + 2 * HALO) * TBLK)   // 72

__global__ __launch_bounds__(256, 8) void fused_halo_kernel(
        const float* __restrict__ x,
        const float* __restrict__ w,
        float* __restrict__ out) {
    const int bid = blockIdx.x;
    const int n   = bid >> 8;          // 256 blocks per image
    const int cb  = (bid >> 4) & 15;   // channel tile
    const int tb  = bid & 15;          // t tile
    const int c0  = cb * CH;
    const int t0  = tb * TBLK;

    const int tid = threadIdx.x;
    const int q   = tid & 3;

    __shared__ float gs[ROWS_TOT];     // [ halo_ci * TBLK + tj ]

    #pragma unroll
    for (int pass = 0; pass < 2; ++pass) {
        const int ri = pass * 64 + (tid >> 2);
        if (ri < ROWS_TOT) {
            const int ci = ri >> 1;            // 0..35 (c = c0-2+ci)
            const int tj = ri & 1;
            const int c  = c0 - HALO + ci;
            float sum = 0.0f;
            if (c >= 0 && c < 512) {
                const int row = (n * 512 + c) * 32 + t0 + tj;
                const float4* p = reinterpret_cast<const float4*>(x) +
                                  (size_t)row * F4_PER_ROW + q;
                float4 a0 = p[0];
                float4 a1 = p[4];
                #pragma unroll
                for (int i = 2; i < 12; i += 2) {
                    float4 u = p[4 * i];
                    float4 v = p[4 * (i + 1)];
                    a0.x += u.x; a0.y += u.y; a0.z += u.z; a0.w += u.w;
                    a1.x += v.x; a1.y += v.y; a1.z += v.z; a1.w += v.w;
                }
                sum = ((a0.x + a1.x) + (a0.y + a1.y)) +
                      ((a0.z + a1.z) + (a0.w + a1.w));
                if (q == 0) {
                    float4 u = p[48];
                    sum += (u.x + u.y) + (u.z + u.w);
                }
            }
            sum += __shfl_xor(sum, 1, 64);
            sum += __shfl_xor(sum, 2, 64);
            if (q == 0) gs[ri] = sum * (1.0f / 196.0f);
        }
    }
    __syncthreads();

    // Phase 2: 64 outputs (32 channels x 2 t), one per thread.
    if (tid < CH * TBLK) {
        const int ci = tid >> 1;   // owned channel index 0..31
        const int tj = tid & 1;
        const float acc =
            w[0] * gs[(ci + 0) * TBLK + tj] +
            w[1] * gs[(ci + 1) * TBLK + tj] +
            w[2] * gs[(ci + 2) * TBLK + tj] +
            w[3] * gs[(ci + 3) * TBLK + tj] +
            w[4] * gs[(ci + 4) * TBLK + tj];
        out[(n * 512 + c0 + ci) * 32 + t0 + tj] = 1.0f / (1.0f + __expf(-acc));
    }
}

extern "C" void kernel_launch(void* const* d_in, const int* in_sizes, int n_in,
                              void* d_out, int out_size, void* d_ws, size_t ws_size,
                              hipStream_t stream) {
    const float* x = (const float*)d_in[0];   // 8*512*32*14*14
    const float* w = (const float*)d_in[1];   // 5
    float* out = (float*)d_out;               // 8*512*32

    fused_halo_kernel<<<2048, 256, 0, stream>>>(x, w, out);
}